// Round 1
// baseline (246.974 us; speedup 1.0000x reference)
//
#include <hip/hip_runtime.h>

typedef unsigned short u16;
typedef unsigned int   u32;
typedef __attribute__((ext_vector_type(8)))  short short8;
typedef __attribute__((ext_vector_type(4)))  float f32x4;
typedef __attribute__((ext_vector_type(16))) float f32x16;
typedef __attribute__((ext_vector_type(2)))  u32 uint2v;
typedef __attribute__((ext_vector_type(4)))  u32 uint4v;

#define DEV __device__ __forceinline__

DEV u16 f2bf(float f) {
    u32 u = __builtin_bit_cast(u32, f);
    return (u16)((u + 0x7fffu + ((u >> 16) & 1u)) >> 16);
}
DEV u32 cvtpk(float a, float b) {
    u32 r;
    asm("v_cvt_pk_bf16_f32 %0, %1, %2" : "=v"(r) : "v"(a), "v"(b));
    return r;
}
typedef const __attribute__((address_space(1))) u32 g_u32;
typedef __attribute__((address_space(3))) u32 l_u32;
DEV void gload16(const u16* g, u16* l) {
    __builtin_amdgcn_global_load_lds((g_u32*)g, (l_u32*)l, 16, 0, 0);
}

// ---------------------------------------------------------------------------
// GEMM: C[4096,1024] = A[4096,1024] @ W[1024,1024] + bias, B pre-transposed
// Wt[n][k] bf16. 128x128 tile, BK=32, 256 thr (4 waves, 2x2), 16x16x32 MFMA.
// AMODE: 0 = A bf16 (global_load_lds), 1 = A f32 (convert in staging)
// OMODE: 0 = bf16 row-major, 1 = bf16 transposed [bh][d][t] (for V), 2 = f32
// ---------------------------------------------------------------------------
template<int AMODE, int OMODE>
DEV void gemm_body(const void* A_, const u16* __restrict__ Bt,
                   const float* __restrict__ bias, void* C_) {
    constexpr int Kd = 1024;
    const int m0 = blockIdx.y * 128, n0 = blockIdx.x * 128;
    const int t = threadIdx.x, lane = t & 63, w = t >> 6;
    const int wm = w >> 1, wn = w & 1;
    const int l15 = lane & 15, l4 = lane >> 4;
    __shared__ __align__(16) u16 As[128 * 32];
    __shared__ __align__(16) u16 Bs[128 * 32];
    f32x4 acc[4][4] = {};

    for (int k0 = 0; k0 < Kd; k0 += 32) {
        // stage B (bf16, linear dest = global_load_lds)
        #pragma unroll
        for (int rnd = 0; rnd < 2; rnd++) {
            int cc = rnd * 256 + t, row = cc >> 2, slot = cc & 3;
            gload16(Bt + (size_t)(n0 + row) * Kd + k0 + slot * 8, Bs + cc * 8);
        }
        // stage A
        if (AMODE == 1) {
            const float* Af = (const float*)A_;
            #pragma unroll
            for (int rnd = 0; rnd < 4; rnd++) {
                int row = (t >> 3) + rnd * 32, c4 = (t & 7) * 4;
                float4 vv = *(const float4*)(Af + (size_t)(m0 + row) * Kd + k0 + c4);
                uint2v pp;
                pp[0] = (u32)f2bf(vv.x) | ((u32)f2bf(vv.y) << 16);
                pp[1] = (u32)f2bf(vv.z) | ((u32)f2bf(vv.w) << 16);
                *(uint2v*)(As + row * 32 + c4) = pp;
            }
        } else {
            const u16* Ab = (const u16*)A_;
            #pragma unroll
            for (int rnd = 0; rnd < 2; rnd++) {
                int cc = rnd * 256 + t, row = cc >> 2, slot = cc & 3;
                gload16(Ab + (size_t)(m0 + row) * Kd + k0 + slot * 8, As + cc * 8);
            }
        }
        __syncthreads();
        short8 af[4], bfr[4];
        #pragma unroll
        for (int i = 0; i < 4; i++) {
            af[i]  = *(const short8*)(As + (wm * 64 + i * 16 + l15) * 32 + l4 * 8);
            bfr[i] = *(const short8*)(Bs + (wn * 64 + i * 16 + l15) * 32 + l4 * 8);
        }
        #pragma unroll
        for (int i = 0; i < 4; i++)
            #pragma unroll
            for (int j = 0; j < 4; j++)
                acc[i][j] = __builtin_amdgcn_mfma_f32_16x16x32_bf16(af[i], bfr[j], acc[i][j], 0, 0, 0);
        __syncthreads();
    }

    #pragma unroll
    for (int i = 0; i < 4; i++) {
        #pragma unroll
        for (int j = 0; j < 4; j++) {
            int col = n0 + wn * 64 + j * 16 + l15;
            int mb  = m0 + wm * 64 + i * 16 + l4 * 4;
            float bv = bias[col];
            if (OMODE == 2) {
                float* C = (float*)C_;
                #pragma unroll
                for (int r = 0; r < 4; r++)
                    C[(size_t)(mb + r) * 1024 + col] = acc[i][j][r] + bv;
            } else if (OMODE == 0) {
                u16* C = (u16*)C_;
                #pragma unroll
                for (int r = 0; r < 4; r++)
                    C[(size_t)(mb + r) * 1024 + col] = f2bf(acc[i][j][r] + bv);
            } else {
                // V: write transposed [bh][d][t], 4 consecutive tokens packed
                u16* C = (u16*)C_;
                int hh = col >> 6, dd = col & 63;
                int bb = mb >> 11, tt = mb & 2047;
                uint2v pp;
                pp[0] = (u32)f2bf(acc[i][j][0] + bv) | ((u32)f2bf(acc[i][j][1] + bv) << 16);
                pp[1] = (u32)f2bf(acc[i][j][2] + bv) | ((u32)f2bf(acc[i][j][3] + bv) << 16);
                *(uint2v*)(C + ((size_t)((bb * 16 + hh) * 64 + dd)) * 2048 + tt) = pp;
            }
        }
    }
}

// weights: W[k][n] f32 -> Wt[n][k] bf16
__global__ __launch_bounds__(256) void k_transw(const float* Wq, const float* Wk,
                                                const float* Wv, const float* Wo, u16* Wt) {
    int z = blockIdx.z;
    const float* W = z == 0 ? Wq : z == 1 ? Wk : z == 2 ? Wv : Wo;
    u16* O = Wt + (size_t)z * 1048576;
    __shared__ float tile[32][33];
    int n0 = blockIdx.x * 32, k0 = blockIdx.y * 32;
    int tx = threadIdx.x, ty = threadIdx.y;
    #pragma unroll
    for (int i = 0; i < 32; i += 8) tile[ty + i][tx] = W[(size_t)(k0 + ty + i) * 1024 + n0 + tx];
    __syncthreads();
    #pragma unroll
    for (int i = 0; i < 32; i += 8) O[(size_t)(n0 + ty + i) * 1024 + k0 + tx] = f2bf(tile[tx][ty + i]);
}

__global__ __launch_bounds__(256) void k_proj(const float* q, const float* k, const float* v,
                                              const u16* Wt, const float* bq, const float* bk,
                                              const float* bv, u16* QKV) {
    int z = blockIdx.z;
    if (z == 2)      gemm_body<1, 1>(v, Wt + (size_t)2 * 1048576, bv, QKV + (size_t)2 * 4194304);
    else if (z == 1) gemm_body<1, 0>(k, Wt + (size_t)1 * 1048576, bk, QKV + (size_t)1 * 4194304);
    else             gemm_body<1, 0>(q, Wt, bq, QKV);
}

__global__ __launch_bounds__(256) void k_gemm_out(const u16* X, const u16* Wt,
                                                  const float* bo, float* out) {
    gemm_body<0, 2>(X, Wt, bo, out);
}

// ---------------------------------------------------------------------------
// Causal flash attention, no-max softmax. grid (T/128, B*H), 256 thr.
// Each wave owns 32 q rows. Swapped QK^T: S^T = mfma(K_frag, Q_frag) so each
// lane holds one q-row's P slice; P->A-frag via cvt_pk_bf16 + permlane32_swap.
// V is pre-transposed in global [bh][64][2048]: PV B-frags are 16B row reads.
// ---------------------------------------------------------------------------
__global__ __launch_bounds__(256) void k_attn(const u16* __restrict__ Qp, const u16* __restrict__ Kp,
                                              const u16* __restrict__ VT, u16* __restrict__ X) {
    const int bh = blockIdx.y, b = bh >> 4, h = bh & 15;
    const int t = threadIdx.x, lane = t & 63, w = t >> 6;
    const int lo = lane & 31, hi = lane >> 5;
    const int q0w = blockIdx.x * 128 + w * 32;
    const u16* Qb = Qp + (size_t)(b * 2048) * 1024 + h * 64;
    const u16* Kb = Kp + (size_t)(b * 2048) * 1024 + h * 64;
    const u16* Vb = VT + (size_t)(bh * 64) * 2048;

    short8 qf[4];
    #pragma unroll
    for (int c = 0; c < 4; c++)
        qf[c] = *(const short8*)(Qb + (size_t)(q0w + lo) * 1024 + c * 16 + hi * 8);

    f32x16 O0 = {}, O1 = {};
    float lsum = 0.f;
    const int qg = q0w + lo;

    for (int k0 = 0; k0 <= q0w; k0 += 32) {
        // S^T[k][q] accumulated over 4 d-chunks
        f32x16 S = {};
        #pragma unroll
        for (int c = 0; c < 4; c++) {
            short8 kf = *(const short8*)(Kb + (size_t)(k0 + lo) * 1024 + c * 16 + hi * 8);
            S = __builtin_amdgcn_mfma_f32_32x32x16_bf16(kf, qf[c], S, 0, 0, 0);
        }
        float p[16];
        bool diag = (k0 == q0w);
        #pragma unroll
        for (int r = 0; r < 16; r++) {
            float s = S[r] * 0.125f;
            if (diag) {
                int kg = k0 + (r & 3) + 8 * (r >> 2) + 4 * hi;
                s = (kg <= qg) ? s : -1e30f;
            }
            p[r] = __expf(s);
            lsum += p[r];
        }
        // P -> bf16 A-frags (k-chunks of 16) + PV
        #pragma unroll
        for (int kc = 0; kc < 2; kc++) {
            u32 w0 = cvtpk(p[8 * kc + 0], p[8 * kc + 1]);
            u32 w1 = cvtpk(p[8 * kc + 2], p[8 * kc + 3]);
            u32 w2 = cvtpk(p[8 * kc + 4], p[8 * kc + 5]);
            u32 w3 = cvtpk(p[8 * kc + 6], p[8 * kc + 7]);
            auto r0 = __builtin_amdgcn_permlane32_swap(w0, w2, false, false);
            auto r1 = __builtin_amdgcn_permlane32_swap(w1, w3, false, false);
            uint4v fw; fw[0] = r0[0]; fw[1] = r1[0]; fw[2] = r0[1]; fw[3] = r1[1];
            short8 pf = __builtin_bit_cast(short8, fw);
            #pragma unroll
            for (int c2 = 0; c2 < 2; c2++) {
                const u16* vp = Vb + (size_t)(c2 * 32 + lo) * 2048 + k0 + kc * 16 + hi * 8;
                short8 vf = *(const short8*)vp;
                if (c2 == 0) O0 = __builtin_amdgcn_mfma_f32_32x32x16_bf16(pf, vf, O0, 0, 0, 0);
                else         O1 = __builtin_amdgcn_mfma_f32_32x32x16_bf16(pf, vf, O1, 0, 0, 0);
            }
        }
    }

    float ltot = lsum + __shfl_xor(lsum, 32, 64);
    #pragma unroll
    for (int r = 0; r < 16; r++) {
        int qr = (r & 3) + 8 * (r >> 2) + 4 * hi;
        float linv = 1.f / __shfl(ltot, qr, 64);
        size_t rowb = (size_t)(b * 2048 + q0w + qr) * 1024 + h * 64;
        X[rowb + lo]      = f2bf(O0[r] * linv);
        X[rowb + 32 + lo] = f2bf(O1[r] * linv);
    }
}

extern "C" void kernel_launch(void* const* d_in, const int* in_sizes, int n_in,
                              void* d_out, int out_size, void* d_ws, size_t ws_size,
                              hipStream_t stream) {
    (void)in_sizes; (void)n_in; (void)out_size; (void)ws_size;
    const float* q  = (const float*)d_in[0];
    const float* k  = (const float*)d_in[1];
    const float* v  = (const float*)d_in[2];
    const float* Wq = (const float*)d_in[3];
    const float* bq = (const float*)d_in[4];
    const float* Wk = (const float*)d_in[5];
    const float* bk = (const float*)d_in[6];
    const float* Wv = (const float*)d_in[7];
    const float* bv = (const float*)d_in[8];
    const float* Wo = (const float*)d_in[9];
    const float* bo = (const float*)d_in[10];

    u16* Wt  = (u16*)d_ws;                      // 4 x 1024x1024 bf16 (8 MB)
    u16* QKV = Wt + (size_t)4 * 1048576;        // 3 x 4096x1024 bf16 (24 MB)
    u16* Xb  = QKV + (size_t)3 * 4194304;       // 4096x1024 bf16 (8 MB)

    k_transw<<<dim3(32, 32, 4), dim3(32, 8), 0, stream>>>(Wq, Wk, Wv, Wo, Wt);
    k_proj<<<dim3(8, 32, 3), 256, 0, stream>>>(q, k, v, Wt, bq, bk, bv, QKV);
    k_attn<<<dim3(16, 32), 256, 0, stream>>>(QKV, QKV + (size_t)4194304,
                                             QKV + (size_t)2 * 4194304, Xb);
    k_gemm_out<<<dim3(8, 32), 256, 0, stream>>>(Xb, Wt + (size_t)3 * 1048576, bo, (float*)d_out);
}